// Round 5
// baseline (232.945 us; speedup 1.0000x reference)
//
#include <hip/hip_runtime.h>
#include <hip/hip_bf16.h>
#include <math.h>

// YOLO decode + hard NMS, exact equivalent of the JAX reference.
// R5: fused pipeline (5 dispatches): memset -> decode(+last-block scal reduce)
// -> hist(+last-block suffix-scan/thresh) -> compact -> nms (single wave,
// bin-ordered chunks, unrolled output argmax). Exact fallback for lower bins.

#define NCLS  80
#define MAXB  100
#define N0    6912     // 48*48*3
#define N1    27648    // 96*96*3
#define NTOT  145152
#define NTILE 2268     // 64-box tiles
#define NHB   567      // hist grid = NTOT/256
#define NB    4096     // histogram bins (linear in score)
#define CAP   2048     // global candidate capacity
#define CAPL  2048     // nms LDS key capacity (fallback)
#define CHUNK 256      // chunk size for nms sort+sweep
#define NEGF  -3.402823466e38f
#define POSF   3.402823466e38f

// ws layout (bytes), ~0.8 MB. Zeroed region: HIST..CTR (one memset).
#define WS_CONF 0
#define WS_SCAL (NTOT * 4)
#define WS_PART (WS_SCAL + 16)
#define WS_SUF  (WS_PART + NTILE * 16)
#define WS_META (WS_SUF + (NB + 2) * 4)
#define WS_CAND (WS_META + 16)
#define WS_HIST (WS_CAND + CAP * 8)          // 8 shards * NB ints
#define WS_BINC (WS_HIST + 8 * NB * 4)       // NB ints
#define WS_CTR  (WS_BINC + NB * 4)           // 2 done-counters
#define WS_ZEROSZ (8 * NB * 4 + NB * 4 + 16)

// Bin index; identical expression everywhere -> identical rounding.
__device__ __forceinline__ int binOf(float s, float Smax) {
    int b = (int)((s / Smax) * (float)NB);
    return b > (NB - 1) ? (NB - 1) : b;
}
__device__ __forceinline__ float smaxOf(const float* scal) {
    float Mx = scal[0], Mn = scal[1], cmx = scal[2], cmn = scal[3];
    return fmaxf(fmaxf(cmx * Mx, cmx * Mn), fmaxf(cmn * Mx, cmn * Mn));
}
__device__ __forceinline__ float rdlane(float v, int l) {
    return __uint_as_float(__builtin_amdgcn_readlane(__float_as_uint(v), l));
}
// Bitwise-identical bbox recompute (same expressions/order as reference decode).
__device__ __forceinline__ void decodeBox(int idx, const float* __restrict__ g0,
        const float* __restrict__ g1, const float* __restrict__ g2,
        const float* __restrict__ anch,
        float& x1, float& y1, float& x2, float& y2) {
    const float* g; int H, ar, j;
    if (idx < N0)           { g = g0; H = 48;  ar = 2; j = idx; }
    else if (idx < N0 + N1) { g = g1; H = 96;  ar = 1; j = idx - N0; }
    else                    { g = g2; H = 192; ar = 0; j = idx - N0 - N1; }
    const float* r = g + (size_t)j * 85;
    float tx = r[0], ty = r[1], tw = r[2], th = r[3];
    int cell = j / 3, a = j - cell * 3;
    int hh = cell / H, ww = cell - hh * H;   // W == H
    float xc = (tx + (float)ww) / (float)H;
    float yc = (ty + (float)hh) / (float)H;
    float bw = expf(tw) * anch[ar * 6 + a * 2];
    float bh = expf(th) * anch[ar * 6 + a * 2 + 1];
    x1 = xc - bw * 0.5f; y1 = yc - bh * 0.5f;
    x2 = xc + bw * 0.5f; y2 = yc + bh * 0.5f;
}

// One 256-thread block per 64-box tile (4 lanes/box). Writes conf + partials;
// last block (threadfence reduction) folds partials -> scal. NO hot atomics.
__global__ __launch_bounds__(256) void k_decode(
        const float* __restrict__ g0, const float* __restrict__ g1,
        const float* __restrict__ g2, float* __restrict__ conf,
        float* __restrict__ part, float* __restrict__ scal,
        int* __restrict__ ctr) {
    __shared__ float sm[5440];                // 64 boxes * 85 ch
    __shared__ float red[16];
    __shared__ int sh_last;
    const int tid = threadIdx.x;
    const int tile = blockIdx.x;
    const float* p; int ibase, lt;
    if (tile < 108)      { p = g0; ibase = 0;       lt = tile; }
    else if (tile < 540) { p = g1; ibase = N0;      lt = tile - 108; }
    else                 { p = g2; ibase = N0 + N1; lt = tile - 540; }
    const float4* src = (const float4*)(p + (size_t)lt * 5440);   // 16B-aligned
    for (int w = tid; w < 1360; w += 256) ((float4*)sm)[w] = src[w];
    __syncthreads();

    const int b = tid >> 2, pp = tid & 3;     // 4 lanes per box, same wave
    const float* row = sm + b * 85;
    float best = row[5 + pp * 20];
    #pragma unroll
    for (int k = 1; k < 20; k++) best = fmaxf(best, row[5 + pp * 20 + k]);
    best = fmaxf(best, __shfl_xor(best, 1));  // full-box max on all 4 lanes
    best = fmaxf(best, __shfl_xor(best, 2));
    float cmx = NEGF, cmn = POSF;
    if (pp == 0) {
        float obj = row[4];
        conf[ibase + lt * 64 + b] = obj;
        cmx = obj; cmn = obj;
    }
    float mpmax = best, mpmin = best;
    for (int off = 32; off; off >>= 1) {
        mpmax = fmaxf(mpmax, __shfl_down(mpmax, off));
        mpmin = fminf(mpmin, __shfl_down(mpmin, off));
        cmx   = fmaxf(cmx,   __shfl_down(cmx,   off));
        cmn   = fminf(cmn,   __shfl_down(cmn,   off));
    }
    const int lane = tid & 63, wid = tid >> 6;
    if (lane == 0) {
        red[wid * 4 + 0] = mpmax; red[wid * 4 + 1] = mpmin;
        red[wid * 4 + 2] = cmx;   red[wid * 4 + 3] = cmn;
    }
    __syncthreads();
    if (tid == 0) {
        float a0 = red[0], a1 = red[1], a2 = red[2], a3 = red[3];
        for (int w = 1; w < 4; w++) {
            a0 = fmaxf(a0, red[w * 4 + 0]); a1 = fminf(a1, red[w * 4 + 1]);
            a2 = fmaxf(a2, red[w * 4 + 2]); a3 = fminf(a3, red[w * 4 + 3]);
        }
        part[tile * 4 + 0] = a0; part[tile * 4 + 1] = a1;
        part[tile * 4 + 2] = a2; part[tile * 4 + 3] = a3;
        __threadfence();                      // release partials
        sh_last = (atomicAdd(&ctr[0], 1) == NTILE - 1);
    }
    __syncthreads();
    if (!sh_last) return;
    __threadfence();                          // acquire all partials
    float a0 = NEGF, a1 = POSF, a2 = NEGF, a3 = POSF;
    for (int t = tid; t < NTILE; t += 256) {
        float4 p4 = ((const float4*)part)[t];
        a0 = fmaxf(a0, p4.x); a1 = fminf(a1, p4.y);
        a2 = fmaxf(a2, p4.z); a3 = fminf(a3, p4.w);
    }
    for (int off = 32; off; off >>= 1) {
        a0 = fmaxf(a0, __shfl_down(a0, off)); a1 = fminf(a1, __shfl_down(a1, off));
        a2 = fmaxf(a2, __shfl_down(a2, off)); a3 = fminf(a3, __shfl_down(a3, off));
    }
    if (lane == 0) {
        red[wid * 4 + 0] = a0; red[wid * 4 + 1] = a1;
        red[wid * 4 + 2] = a2; red[wid * 4 + 3] = a3;
    }
    __syncthreads();
    if (tid == 0) {
        for (int w = 1; w < 4; w++) {
            a0 = fmaxf(a0, red[w * 4 + 0]); a1 = fminf(a1, red[w * 4 + 1]);
            a2 = fmaxf(a2, red[w * 4 + 2]); a3 = fminf(a3, red[w * 4 + 3]);
        }
        scal[0] = a0; scal[1] = a1; scal[2] = a2; scal[3] = a3;
    }
}

// Sharded histogram; last block (threadfence) sums shards, suffix-scans -> suf,
// binary-searches threshold -> meta.
__global__ __launch_bounds__(256) void k_hist(
        const float* __restrict__ conf, const float* __restrict__ scal,
        int* __restrict__ hist, int* __restrict__ ctr,
        int* __restrict__ suf, int* __restrict__ meta) {
    const int tid = threadIdx.x;
    __shared__ int sh_last;
    __shared__ int grp[256];
    {
        int i = blockIdx.x * 256 + tid;       // grid == NTOT/256 exactly
        float Mx = scal[0], Mn = scal[1];
        float Smax = smaxOf(scal);
        float c = conf[i];
        float s = fmaxf(c * Mx, c * Mn);      // == max_j conf_i * maxprob_j
        if (s > 0.0f && Smax > 0.0f)          // 8-way sharded to spread lines
            atomicAdd(&hist[((blockIdx.x & 7) << 12) + binOf(s, Smax)], 1);
    }
    __threadfence();                          // release this block's atomics
    if (tid == 0) sh_last = (atomicAdd(&ctr[1], 1) == NHB - 1);
    __syncthreads();
    if (!sh_last) return;
    __threadfence();                          // acquire all shards
    int b0 = tid * 16;
    int h[16], tot = 0;
    #pragma unroll
    for (int q = 0; q < 16; q++) {
        int ss = 0;
        #pragma unroll
        for (int sh = 0; sh < 8; sh++) ss += hist[sh * NB + b0 + q];
        h[q] = ss; tot += ss;
    }
    grp[tid] = tot;
    __syncthreads();
    for (int d = 1; d < 256; d <<= 1) {       // Hillis-Steele suffix scan
        int add = (tid + d < 256) ? grp[tid + d] : 0;
        __syncthreads();
        grp[tid] += add;
        __syncthreads();
    }
    int run = (tid + 1 < 256) ? grp[tid + 1] : 0;
    #pragma unroll
    for (int q = 15; q >= 0; q--) { run += h[q]; suf[b0 + q] = run; }
    if (tid == 0) suf[NB] = 0;
    __syncthreads();                          // suf visible block-wide
    if (tid == 0) {                           // min lo with suffix count <= CAP
        int L = 0, R = NB - 1, res = NB - 1;
        while (L <= R) {
            int m = (L + R) >> 1;
            if (suf[m] <= CAP) { res = m; R = m - 1; } else L = m + 1;
        }
        meta[0] = res;
    }
}

__global__ __launch_bounds__(256) void k_compact(
        const float* __restrict__ conf, const float* __restrict__ scal,
        const int* __restrict__ suf, const int* __restrict__ meta,
        int* __restrict__ binCtr, unsigned long long* __restrict__ cand) {
    int i = blockIdx.x * 256 + threadIdx.x;
    float Mx = scal[0], Mn = scal[1];
    float Smax = smaxOf(scal);
    float c = conf[i];
    float s = fmaxf(c * Mx, c * Mn);
    int lo = meta[0];
    if (s > 0.0f && Smax > 0.0f) {
        int b = binOf(s, Smax);
        if (b >= lo) {
            // exact position: (#cands in higher bins) + rank within bin
            int pos = suf[b + 1] + atomicAdd(&binCtr[b], 1);
            if (pos < CAP)
                // key: score bits | ~idx (ties: smallest idx first in desc sort)
                cand[pos] = ((unsigned long long)__float_as_uint(s) << 32)
                          | (unsigned long long)(~(unsigned)i);
        }
    }
}

// Single wave. Consumes cand[] (bin-descending order) in bin-aligned chunks.
__global__ __launch_bounds__(64) void k_nms(
        const float* __restrict__ g0, const float* __restrict__ g1,
        const float* __restrict__ g2, const float* __restrict__ anch,
        const float* __restrict__ conf, const float* __restrict__ scal,
        const int* __restrict__ suf, const int* __restrict__ meta,
        const unsigned long long* __restrict__ cand, float* __restrict__ out) {
    __shared__ unsigned long long keys[CAPL]; // 16 KB
    __shared__ float selX1[MAXB], selY1[MAXB], selX2[MAXB], selY2[MAXB],
                     selA[MAXB], selS[MAXB];
    __shared__ int selIdx[MAXB];
    __shared__ int sh_cnt;

    const int lane = threadIdx.x;
    const float Mx = scal[0], Mn = scal[1];
    const float Smax = smaxOf(scal);
    const int loGlob = meta[0];
    int nsel = 0;
    int hi = NB;

    while (nsel < MAXB && hi > 0) {
        const bool fast = hi > loGlob;        // cand[] covers bins >= loGlob
        const int sufHi = suf[hi];
        int l;
        {   // min l in [lb, hi) with chunk count <= cap (single over-full bin ok)
            int lb = fast ? loGlob : 0;
            int capHere = fast ? CHUNK : CAPL;
            int L = lb, R = hi - 1, res = hi - 1;
            while (L <= R) {
                int m = (L + R) >> 1;
                if (suf[m] - sufHi <= capHere) { res = m; R = m - 1; } else L = m + 1;
            }
            l = res;                          // l < hi: guaranteed progress
        }
        int cnt;
        if (fast) {
            cnt = suf[l] - sufHi;
            for (int i = lane; i < cnt; i += 64) keys[i] = cand[sufHi + i];
        } else {                              // exact fallback (cold path)
            if (lane == 0) sh_cnt = 0;
            __syncthreads();
            for (int i = lane; i < NTOT; i += 64) {
                float c = conf[i];
                float s = fmaxf(c * Mx, c * Mn);
                if (s > 0.0f) {
                    int b = binOf(s, Smax);
                    if (b >= l && b < hi) {
                        int pos = atomicAdd(&sh_cnt, 1);
                        if (pos < CAPL)
                            keys[pos] = ((unsigned long long)__float_as_uint(s) << 32)
                                      | (unsigned long long)(~(unsigned)i);
                    }
                }
            }
            __syncthreads();
            cnt = sh_cnt; if (cnt > CAPL) cnt = CAPL;
        }
        if (cnt > 0) {
            int n = 2; while (n < cnt) n <<= 1;
            for (int i = cnt + lane; i < n; i += 64) keys[i] = 0ULL;
            __syncthreads();
            // bitonic sort, descending; enumerate pair-slots directly
            for (int k = 2; k <= n; k <<= 1) {
                for (int j = k >> 1; j > 0; j >>= 1) {
                    int half = n >> 1;
                    for (int t = lane; t < half; t += 64) {
                        int i = ((t & ~(j - 1)) << 1) | (t & (j - 1));
                        int ixj = i | j;
                        unsigned long long ka = keys[i], kb = keys[ixj];
                        if ((ka < kb) == ((i & k) == 0)) { keys[i] = kb; keys[ixj] = ka; }
                    }
                    __syncthreads();          // 1-wave block: cheap
                }
            }
            // sweep in 64-wide waves; v_readlane accept loop
            for (int bpos = 0; bpos < cnt && nsel < MAXB; bpos += 64) {
                int t = bpos + lane;
                bool alive = (t < cnt);
                float x1 = 0.f, y1 = 0.f, x2 = 0.f, y2 = 0.f, area = 0.f, sc = 0.f;
                int idx = 0;
                if (alive) {
                    unsigned long long key = keys[t];
                    idx = (int)(~(unsigned)key);
                    sc = __uint_as_float((unsigned)(key >> 32));
                    decodeBox(idx, g0, g1, g2, anch, x1, y1, x2, y2);
                    area = (x2 - x1) * (y2 - y1);
                    for (int s2 = 0; s2 < nsel; s2++) {   // pre-test vs prior sels
                        float iw = fminf(x2, selX2[s2]) - fmaxf(x1, selX1[s2]);
                        float ih = fminf(y2, selY2[s2]) - fmaxf(y1, selY1[s2]);
                        iw = fmaxf(iw, 0.f); ih = fmaxf(ih, 0.f);
                        float inter = iw * ih;
                        if (inter / (area + selA[s2] - inter) > 0.5f) { alive = false; break; }
                    }
                }
                while (nsel < MAXB) {
                    unsigned long long bal = __ballot(alive);
                    if (!bal) break;
                    int w = __ffsll((unsigned long long)bal) - 1;
                    float wx1 = rdlane(x1, w), wy1 = rdlane(y1, w);
                    float wx2 = rdlane(x2, w), wy2 = rdlane(y2, w);
                    float wa  = rdlane(area, w);
                    if (lane == w) {          // winner stores its own entry
                        selX1[nsel] = x1; selY1[nsel] = y1;
                        selX2[nsel] = x2; selY2[nsel] = y2;
                        selA[nsel] = area; selS[nsel] = sc; selIdx[nsel] = idx;
                    }
                    if (alive) {              // winner kills itself (IoU=1)
                        float iw = fminf(x2, wx2) - fmaxf(x1, wx1);
                        float ih = fminf(y2, wy2) - fmaxf(y1, wy1);
                        iw = fmaxf(iw, 0.f); ih = fmaxf(ih, 0.f);
                        float inter = iw * ih;
                        if (inter / (area + wa - inter) > 0.5f) alive = false;
                    }
                    nsel++;
                }
                __syncthreads();
            }
        }
        hi = l;
    }
    __syncthreads();

    // outputs: boxes[100*4] | scores[100] | classes[100] | num_valid (all fp32)
    for (int k = lane; k < MAXB; k += 64) {
        float b0 = 0.f, b1 = 0.f, b2 = 0.f, b3 = 0.f, sv = 0.f, cv = 0.f;
        if (k < nsel) {
            b0 = selX1[k]; b1 = selY1[k]; b2 = selX2[k]; b3 = selY2[k];
            sv = selS[k];
            int idx = selIdx[k];              // class argmax only for selected
            const float* g; int j;
            if (idx < N0)           { g = g0; j = idx; }
            else if (idx < N0 + N1) { g = g1; j = idx - N0; }
            else                    { g = g2; j = idx - N0 - N1; }
            const float* r = g + (size_t)j * 85 + 5;
            float v[NCLS];
            #pragma unroll                    // all 80 loads in flight, one wait
            for (int q = 0; q < NCLS; q++) v[q] = r[q];
            float best = v[0]; int c = 0;
            #pragma unroll
            for (int q = 1; q < NCLS; q++)
                if (v[q] > best) { best = v[q]; c = q; }   // strict > = first max
            cv = (float)c;
        }
        out[4 * k + 0] = b0; out[4 * k + 1] = b1;
        out[4 * k + 2] = b2; out[4 * k + 3] = b3;
        out[400 + k] = sv;
        out[500 + k] = cv;
    }
    if (lane == 0) out[600] = (float)nsel;
}

extern "C" void kernel_launch(void* const* d_in, const int* in_sizes, int n_in,
                              void* d_out, int out_size, void* d_ws, size_t ws_size,
                              hipStream_t stream) {
    const float* g0   = (const float*)d_in[0];
    const float* g1   = (const float*)d_in[1];
    const float* g2   = (const float*)d_in[2];
    const float* anch = (const float*)d_in[3];
    char* ws = (char*)d_ws;
    float* conf  = (float*)(ws + WS_CONF);
    float* scal  = (float*)(ws + WS_SCAL);
    float* part  = (float*)(ws + WS_PART);
    int*   suf   = (int*)(ws + WS_SUF);
    int*   meta  = (int*)(ws + WS_META);
    unsigned long long* cand = (unsigned long long*)(ws + WS_CAND);
    int*   hist  = (int*)(ws + WS_HIST);
    int*   binc  = (int*)(ws + WS_BINC);
    int*   ctr   = (int*)(ws + WS_CTR);
    float* out   = (float*)d_out;

    hipMemsetAsync(ws + WS_HIST, 0, WS_ZEROSZ, stream);   // hist+binCtr+ctrs
    k_decode <<<NTILE, 256, 0, stream>>>(g0, g1, g2, conf, part, scal, ctr);
    k_hist   <<<NHB, 256, 0, stream>>>(conf, scal, hist, ctr, suf, meta);
    k_compact<<<NHB, 256, 0, stream>>>(conf, scal, suf, meta, binc, cand);
    k_nms    <<<1, 64, 0, stream>>>(g0, g1, g2, anch, conf, scal, suf, meta, cand, out);
}

// Round 6
// 161.289 us; speedup vs baseline: 1.4443x; 1.4443x over previous
//
#include <hip/hip_runtime.h>
#include <hip/hip_bf16.h>
#include <math.h>

// YOLO decode + hard NMS, exact equivalent of the JAX reference.
// R6: R4 pipeline restored (no done-counters — same-line device atomics cost
// ~20-50ns each serialized; thousands of them = tens of us). Only retained
// R5 change: k_nms output argmax unrolled (batch loads, one wait).

#define NCLS  80
#define MAXB  100
#define N0    6912     // 48*48*3
#define N1    27648    // 96*96*3
#define NTOT  145152
#define NTILE 2268     // 64-box tiles
#define NB    4096     // histogram bins (linear in score)
#define CAP   2048     // global candidate capacity
#define CAPL  2048     // nms LDS key capacity (fallback)
#define CHUNK 256      // target chunk size for nms sort+sweep
#define NEGF  -3.402823466e38f
#define POSF   3.402823466e38f

// ws layout (bytes), ~0.8 MB
#define WS_CONF 0
#define WS_SCAL (NTOT * 4)
#define WS_PART (WS_SCAL + 16)
#define WS_HIST (WS_PART + NTILE * 16)       // 8 shards * NB ints
#define WS_BINC (WS_HIST + 8 * NB * 4)       // NB ints (contiguous after HIST)
#define WS_SUF  (WS_BINC + NB * 4)
#define WS_META (WS_SUF + (NB + 2) * 4)
#define WS_CAND (WS_META + 16)

// Bin index; identical expression everywhere -> identical rounding.
__device__ __forceinline__ int binOf(float s, float Smax) {
    int b = (int)((s / Smax) * (float)NB);
    return b > (NB - 1) ? (NB - 1) : b;
}
__device__ __forceinline__ float smaxOf(const float* scal) {
    float Mx = scal[0], Mn = scal[1], cmx = scal[2], cmn = scal[3];
    return fmaxf(fmaxf(cmx * Mx, cmx * Mn), fmaxf(cmn * Mx, cmn * Mn));
}
__device__ __forceinline__ float rdlane(float v, int l) {
    return __uint_as_float(__builtin_amdgcn_readlane(__float_as_uint(v), l));
}
// Bitwise-identical bbox recompute (same expressions/order as reference decode).
__device__ __forceinline__ void decodeBox(int idx, const float* __restrict__ g0,
        const float* __restrict__ g1, const float* __restrict__ g2,
        const float* __restrict__ anch,
        float& x1, float& y1, float& x2, float& y2) {
    const float* g; int H, ar, j;
    if (idx < N0)           { g = g0; H = 48;  ar = 2; j = idx; }
    else if (idx < N0 + N1) { g = g1; H = 96;  ar = 1; j = idx - N0; }
    else                    { g = g2; H = 192; ar = 0; j = idx - N0 - N1; }
    const float* r = g + (size_t)j * 85;
    float tx = r[0], ty = r[1], tw = r[2], th = r[3];
    int cell = j / 3, a = j - cell * 3;
    int hh = cell / H, ww = cell - hh * H;   // W == H
    float xc = (tx + (float)ww) / (float)H;
    float yc = (ty + (float)hh) / (float)H;
    float bw = expf(tw) * anch[ar * 6 + a * 2];
    float bh = expf(th) * anch[ar * 6 + a * 2 + 1];
    x1 = xc - bw * 0.5f; y1 = yc - bh * 0.5f;
    x2 = xc + bw * 0.5f; y2 = yc + bh * 0.5f;
}

// One 256-thread block per 64-box tile: 4 lanes per box. Writes conf + partials.
__global__ __launch_bounds__(256) void k_decode(
        const float* __restrict__ g0, const float* __restrict__ g1,
        const float* __restrict__ g2, float* __restrict__ conf,
        float* __restrict__ part) {
    __shared__ float sm[5440];                // 64 boxes * 85 ch
    __shared__ float red[16];
    const int tid = threadIdx.x;
    const int tile = blockIdx.x;
    const float* p; int ibase, lt;
    if (tile < 108)      { p = g0; ibase = 0;       lt = tile; }
    else if (tile < 540) { p = g1; ibase = N0;      lt = tile - 108; }
    else                 { p = g2; ibase = N0 + N1; lt = tile - 540; }
    const float4* src = (const float4*)(p + (size_t)lt * 5440);   // 16B-aligned
    for (int w = tid; w < 1360; w += 256) ((float4*)sm)[w] = src[w];
    __syncthreads();

    const int b = tid >> 2, pp = tid & 3;     // 4 lanes per box, same wave
    const float* row = sm + b * 85;
    float best = row[5 + pp * 20];
    #pragma unroll
    for (int k = 1; k < 20; k++) best = fmaxf(best, row[5 + pp * 20 + k]);
    best = fmaxf(best, __shfl_xor(best, 1));  // full-box max on all 4 lanes
    best = fmaxf(best, __shfl_xor(best, 2));
    float cmx = NEGF, cmn = POSF;
    if (pp == 0) {
        float obj = row[4];
        conf[ibase + lt * 64 + b] = obj;
        cmx = obj; cmn = obj;
    }
    // block reduce {max/min box-max, max/min conf} -> plain stores (NO atomics)
    float mpmax = best, mpmin = best;
    for (int off = 32; off; off >>= 1) {
        mpmax = fmaxf(mpmax, __shfl_down(mpmax, off));
        mpmin = fminf(mpmin, __shfl_down(mpmin, off));
        cmx   = fmaxf(cmx,   __shfl_down(cmx,   off));
        cmn   = fminf(cmn,   __shfl_down(cmn,   off));
    }
    const int lane = tid & 63, wid = tid >> 6;
    if (lane == 0) {
        red[wid * 4 + 0] = mpmax; red[wid * 4 + 1] = mpmin;
        red[wid * 4 + 2] = cmx;   red[wid * 4 + 3] = cmn;
    }
    __syncthreads();
    if (tid == 0) {
        float a0 = red[0], a1 = red[1], a2 = red[2], a3 = red[3];
        for (int w = 1; w < 4; w++) {
            a0 = fmaxf(a0, red[w * 4 + 0]); a1 = fminf(a1, red[w * 4 + 1]);
            a2 = fmaxf(a2, red[w * 4 + 2]); a3 = fminf(a3, red[w * 4 + 3]);
        }
        part[tile * 4 + 0] = a0; part[tile * 4 + 1] = a1;
        part[tile * 4 + 2] = a2; part[tile * 4 + 3] = a3;
    }
}

__global__ __launch_bounds__(256) void k_reduce(const float* __restrict__ part,
                                                float* __restrict__ scal) {
    __shared__ float red[16];
    const int tid = threadIdx.x;
    float a0 = NEGF, a1 = POSF, a2 = NEGF, a3 = POSF;
    for (int b = tid; b < NTILE; b += 256) {
        float4 p4 = ((const float4*)part)[b];
        a0 = fmaxf(a0, p4.x); a1 = fminf(a1, p4.y);
        a2 = fmaxf(a2, p4.z); a3 = fminf(a3, p4.w);
    }
    for (int off = 32; off; off >>= 1) {
        a0 = fmaxf(a0, __shfl_down(a0, off)); a1 = fminf(a1, __shfl_down(a1, off));
        a2 = fmaxf(a2, __shfl_down(a2, off)); a3 = fminf(a3, __shfl_down(a3, off));
    }
    const int lane = tid & 63, wid = tid >> 6;
    if (lane == 0) {
        red[wid * 4 + 0] = a0; red[wid * 4 + 1] = a1;
        red[wid * 4 + 2] = a2; red[wid * 4 + 3] = a3;
    }
    __syncthreads();
    if (tid == 0) {
        for (int w = 1; w < 4; w++) {
            a0 = fmaxf(a0, red[w * 4 + 0]); a1 = fminf(a1, red[w * 4 + 1]);
            a2 = fmaxf(a2, red[w * 4 + 2]); a3 = fminf(a3, red[w * 4 + 3]);
        }
        scal[0] = a0; scal[1] = a1; scal[2] = a2; scal[3] = a3;
    }
}

__global__ __launch_bounds__(256) void k_hist(const float* __restrict__ conf,
                                              const float* __restrict__ scal,
                                              int* __restrict__ hist) {
    int i = blockIdx.x * 256 + threadIdx.x;   // grid == NTOT/256 exactly
    float Mx = scal[0], Mn = scal[1];
    float Smax = smaxOf(scal);
    float c = conf[i];
    float s = fmaxf(c * Mx, c * Mn);          // == max_j conf_i * maxprob_j
    if (s > 0.0f && Smax > 0.0f)              // 8-way sharded to spread lines
        atomicAdd(&hist[((blockIdx.x & 7) << 12) + binOf(s, Smax)], 1);
}

__global__ __launch_bounds__(1024) void k_thresh(const int* __restrict__ hist,
                                                 int* __restrict__ suf,
                                                 int* __restrict__ meta) {
    __shared__ int grp[1024];
    const int tid = threadIdx.x;
    int b0 = tid * 4;
    int h[4];
    #pragma unroll
    for (int q = 0; q < 4; q++) {             // sum the 8 shards
        int s = 0;
        #pragma unroll
        for (int sh = 0; sh < 8; sh++) s += hist[sh * NB + b0 + q];
        h[q] = s;
    }
    grp[tid] = h[0] + h[1] + h[2] + h[3];
    __syncthreads();
    for (int d = 1; d < 1024; d <<= 1) {      // Hillis-Steele suffix scan
        int add = (tid + d < 1024) ? grp[tid + d] : 0;
        __syncthreads();
        grp[tid] += add;
        __syncthreads();
    }
    int gnext = (tid + 1 < 1024) ? grp[tid + 1] : 0;
    suf[b0 + 3] = gnext + h[3];
    suf[b0 + 2] = gnext + h[3] + h[2];
    suf[b0 + 1] = gnext + h[3] + h[2] + h[1];
    suf[b0 + 0] = gnext + h[3] + h[2] + h[1] + h[0];
    if (tid == 0) suf[NB] = 0;
    __syncthreads();
    if (tid == 0) {                           // min lo with suffix count <= CAP
        int L = 0, R = NB - 1, res = NB - 1;
        while (L <= R) {
            int m = (L + R) >> 1;
            if (suf[m] <= CAP) { res = m; R = m - 1; } else L = m + 1;
        }
        meta[0] = res;
    }
}

__global__ __launch_bounds__(256) void k_compact(
        const float* __restrict__ conf, const float* __restrict__ scal,
        const int* __restrict__ suf, const int* __restrict__ meta,
        int* __restrict__ binCtr, unsigned long long* __restrict__ cand) {
    int i = blockIdx.x * 256 + threadIdx.x;
    float Mx = scal[0], Mn = scal[1];
    float Smax = smaxOf(scal);
    float c = conf[i];
    float s = fmaxf(c * Mx, c * Mn);
    int lo = meta[0];
    if (s > 0.0f && Smax > 0.0f) {
        int b = binOf(s, Smax);
        if (b >= lo) {
            // exact position: (#cands in higher bins) + rank within bin
            int pos = suf[b + 1] + atomicAdd(&binCtr[b], 1);
            if (pos < CAP)
                // key: score bits | ~idx (ties: smallest idx first in desc sort)
                cand[pos] = ((unsigned long long)__float_as_uint(s) << 32)
                          | (unsigned long long)(~(unsigned)i);
        }
    }
}

// Single wave. Consumes cand[] (bin-descending order) in bin-aligned chunks.
__global__ __launch_bounds__(64) void k_nms(
        const float* __restrict__ g0, const float* __restrict__ g1,
        const float* __restrict__ g2, const float* __restrict__ anch,
        const float* __restrict__ conf, const float* __restrict__ scal,
        const int* __restrict__ suf, const int* __restrict__ meta,
        const unsigned long long* __restrict__ cand, float* __restrict__ out) {
    __shared__ unsigned long long keys[CAPL]; // 16 KB
    __shared__ float selX1[MAXB], selY1[MAXB], selX2[MAXB], selY2[MAXB],
                     selA[MAXB], selS[MAXB];
    __shared__ int selIdx[MAXB];
    __shared__ int sh_cnt;

    const int lane = threadIdx.x;
    const float Mx = scal[0], Mn = scal[1];
    const float Smax = smaxOf(scal);
    const int loGlob = meta[0];
    int nsel = 0;
    int hi = NB;

    while (nsel < MAXB && hi > 0) {
        const bool fast = hi > loGlob;        // cand[] covers bins >= loGlob
        const int sufHi = suf[hi];
        int l;
        {   // min l in [lb, hi) with chunk count <= cap (single over-full bin ok)
            int lb = fast ? loGlob : 0;
            int capHere = fast ? CHUNK : CAPL;
            int L = lb, R = hi - 1, res = hi - 1;
            while (L <= R) {
                int m = (L + R) >> 1;
                if (suf[m] - sufHi <= capHere) { res = m; R = m - 1; } else L = m + 1;
            }
            l = res;                          // l < hi: guaranteed progress
        }
        int cnt;
        if (fast) {
            cnt = suf[l] - sufHi;
            for (int i = lane; i < cnt; i += 64) keys[i] = cand[sufHi + i];
        } else {                              // exact fallback (cold path)
            if (lane == 0) sh_cnt = 0;
            __syncthreads();
            for (int i = lane; i < NTOT; i += 64) {
                float c = conf[i];
                float s = fmaxf(c * Mx, c * Mn);
                if (s > 0.0f) {
                    int b = binOf(s, Smax);
                    if (b >= l && b < hi) {
                        int pos = atomicAdd(&sh_cnt, 1);
                        if (pos < CAPL)
                            keys[pos] = ((unsigned long long)__float_as_uint(s) << 32)
                                      | (unsigned long long)(~(unsigned)i);
                    }
                }
            }
            __syncthreads();
            cnt = sh_cnt; if (cnt > CAPL) cnt = CAPL;
        }
        if (cnt > 0) {
            int n = 2; while (n < cnt) n <<= 1;
            for (int i = cnt + lane; i < n; i += 64) keys[i] = 0ULL;
            __syncthreads();
            // bitonic sort, descending; enumerate pair-slots directly
            for (int k = 2; k <= n; k <<= 1) {
                for (int j = k >> 1; j > 0; j >>= 1) {
                    int half = n >> 1;
                    for (int t = lane; t < half; t += 64) {
                        int i = ((t & ~(j - 1)) << 1) | (t & (j - 1));
                        int ixj = i | j;
                        unsigned long long ka = keys[i], kb = keys[ixj];
                        if ((ka < kb) == ((i & k) == 0)) { keys[i] = kb; keys[ixj] = ka; }
                    }
                    __syncthreads();          // 1-wave block: cheap
                }
            }
            // sweep in 64-wide waves; v_readlane accept loop
            for (int bpos = 0; bpos < cnt && nsel < MAXB; bpos += 64) {
                int t = bpos + lane;
                bool alive = (t < cnt);
                float x1 = 0.f, y1 = 0.f, x2 = 0.f, y2 = 0.f, area = 0.f, sc = 0.f;
                int idx = 0;
                if (alive) {
                    unsigned long long key = keys[t];
                    idx = (int)(~(unsigned)key);
                    sc = __uint_as_float((unsigned)(key >> 32));
                    decodeBox(idx, g0, g1, g2, anch, x1, y1, x2, y2);
                    area = (x2 - x1) * (y2 - y1);
                    for (int s2 = 0; s2 < nsel; s2++) {   // pre-test vs prior sels
                        float iw = fminf(x2, selX2[s2]) - fmaxf(x1, selX1[s2]);
                        float ih = fminf(y2, selY2[s2]) - fmaxf(y1, selY1[s2]);
                        iw = fmaxf(iw, 0.f); ih = fmaxf(ih, 0.f);
                        float inter = iw * ih;
                        if (inter / (area + selA[s2] - inter) > 0.5f) { alive = false; break; }
                    }
                }
                while (nsel < MAXB) {
                    unsigned long long bal = __ballot(alive);
                    if (!bal) break;
                    int w = __ffsll((unsigned long long)bal) - 1;
                    float wx1 = rdlane(x1, w), wy1 = rdlane(y1, w);
                    float wx2 = rdlane(x2, w), wy2 = rdlane(y2, w);
                    float wa  = rdlane(area, w);
                    if (lane == w) {          // winner stores its own entry
                        selX1[nsel] = x1; selY1[nsel] = y1;
                        selX2[nsel] = x2; selY2[nsel] = y2;
                        selA[nsel] = area; selS[nsel] = sc; selIdx[nsel] = idx;
                    }
                    if (alive) {              // winner kills itself (IoU=1)
                        float iw = fminf(x2, wx2) - fmaxf(x1, wx1);
                        float ih = fminf(y2, wy2) - fmaxf(y1, wy1);
                        iw = fmaxf(iw, 0.f); ih = fmaxf(ih, 0.f);
                        float inter = iw * ih;
                        if (inter / (area + wa - inter) > 0.5f) alive = false;
                    }
                    nsel++;
                }
                __syncthreads();
            }
        }
        hi = l;
    }
    __syncthreads();

    // outputs: boxes[100*4] | scores[100] | classes[100] | num_valid (all fp32)
    for (int k = lane; k < MAXB; k += 64) {
        float b0 = 0.f, b1 = 0.f, b2 = 0.f, b3 = 0.f, sv = 0.f, cv = 0.f;
        if (k < nsel) {
            b0 = selX1[k]; b1 = selY1[k]; b2 = selX2[k]; b3 = selY2[k];
            sv = selS[k];
            int idx = selIdx[k];              // class argmax only for selected
            const float* g; int j;
            if (idx < N0)           { g = g0; j = idx; }
            else if (idx < N0 + N1) { g = g1; j = idx - N0; }
            else                    { g = g2; j = idx - N0 - N1; }
            const float* r = g + (size_t)j * 85 + 5;
            float v[NCLS];
            #pragma unroll                    // all 80 loads in flight, one wait
            for (int q = 0; q < NCLS; q++) v[q] = r[q];
            float best = v[0]; int c = 0;
            #pragma unroll
            for (int q = 1; q < NCLS; q++)
                if (v[q] > best) { best = v[q]; c = q; }   // strict > = first max
            cv = (float)c;
        }
        out[4 * k + 0] = b0; out[4 * k + 1] = b1;
        out[4 * k + 2] = b2; out[4 * k + 3] = b3;
        out[400 + k] = sv;
        out[500 + k] = cv;
    }
    if (lane == 0) out[600] = (float)nsel;
}

extern "C" void kernel_launch(void* const* d_in, const int* in_sizes, int n_in,
                              void* d_out, int out_size, void* d_ws, size_t ws_size,
                              hipStream_t stream) {
    const float* g0   = (const float*)d_in[0];
    const float* g1   = (const float*)d_in[1];
    const float* g2   = (const float*)d_in[2];
    const float* anch = (const float*)d_in[3];
    char* ws = (char*)d_ws;
    float* conf  = (float*)(ws + WS_CONF);
    float* scal  = (float*)(ws + WS_SCAL);
    float* part  = (float*)(ws + WS_PART);
    int*   hist  = (int*)(ws + WS_HIST);
    int*   binc  = (int*)(ws + WS_BINC);
    int*   suf   = (int*)(ws + WS_SUF);
    int*   meta  = (int*)(ws + WS_META);
    unsigned long long* cand = (unsigned long long*)(ws + WS_CAND);
    float* out   = (float*)d_out;

    hipMemsetAsync(ws + WS_HIST, 0, 9 * NB * 4, stream);    // hist shards + binCtr
    k_decode <<<NTILE, 256, 0, stream>>>(g0, g1, g2, conf, part);
    k_reduce <<<1, 256, 0, stream>>>(part, scal);
    k_hist   <<<NTOT / 256, 256, 0, stream>>>(conf, scal, hist);
    k_thresh <<<1, 1024, 0, stream>>>(hist, suf, meta);
    k_compact<<<NTOT / 256, 256, 0, stream>>>(conf, scal, suf, meta, binc, cand);
    k_nms    <<<1, 64, 0, stream>>>(g0, g1, g2, anch, conf, scal, suf, meta, cand, out);
}